// Round 5
// baseline (302.326 us; speedup 1.0000x reference)
//
#include <hip/hip_runtime.h>
#include <math.h>

#define TLEN 512
#define NCH  128
#define KP   4
#define PMAXV 64
#define CMAXV 32
#define MINP 16
#define NSEQ 4096   // B*N = 32*128
#define OUTG ((size_t)NSEQ * KP * CMAXV * PMAXV)   // 33,554,432

// LDS bank-conflict padding: insert one element every 16
#define PAD(i) ((i) + ((i) >> 4))

// native vector type for nontemporal builtin (HIP float4 is a struct)
typedef float nfloat4 __attribute__((ext_vector_type(4)));

// ---- tiny setup kernel: twiddle table W[j] = exp(-2*pi*i*j/512) into ws ----
__global__ void twiddle_setup(double2* __restrict__ Wg) {
    const int j = threadIdx.x;    // 256 threads
    double ang = -6.283185307179586476925286766559 * (double)j / (double)TLEN;
    double sv, cv;
    sincos(ang, &sv, &cv);
    Wg[j] = make_double2(cv, sv);
}

// ============================================================================
// Kernel 1: per-sequence FFT + top-4 -> params. NO bulk output stores.
// Writes: de-strided sequence (seq_ws), {P,cyc,base} per (s,k) (prm_ws), kamp.
// ============================================================================
__global__ __launch_bounds__(256) void param_kernel(
    const float* __restrict__ x,
    const double2* __restrict__ Wg,
    float* __restrict__ seq_ws,      // [NSEQ][TLEN]
    int4*  __restrict__ prm_ws,      // [NSEQ][KP]
    float* __restrict__ out_a)       // [NSEQ][KP]
{
    const int s    = blockIdx.x;     // sequence id 0..4095
    const int tid  = threadIdx.x;    // 0..255
    const int lane = tid & 63;
    const int wave = tid >> 6;

    __shared__ float   seqf[TLEN];
    __shared__ double2 X[TLEN + (TLEN >> 4)];        // padded (544)
    __shared__ double2 W[256 + 16];                  // padded (272)
    __shared__ double  amp2[280];                    // PAD(256)=272 used
    __shared__ double  bestv[KP];
    __shared__ int     besti[KP];

    // ---- load column x[b, :, n] + twiddle table from ws ----
    const int b = s >> 7;            // / NCH
    const int n = s & (NCH - 1);
    const float* col = x + (size_t)b * TLEN * NCH + n;
    for (int i = tid; i < TLEN; i += 256)
        seqf[i] = col[(size_t)i * NCH];
    W[PAD(tid)] = Wg[tid];           // L2-hot broadcast load
    __syncthreads();   // B1

    // de-strided sequence out (coalesced, L2->writer kernel)
    for (int i = tid; i < TLEN; i += 256)
        seq_ws[(size_t)s * TLEN + i] = seqf[i];

    // ---- wave-local bit-reverse scatter into own 128-pt chunk ----
    {
        const int base = wave << 7;
        int i0 = base + lane, i1 = base + 64 + lane;
        int r0 = (int)(__brev((unsigned)i0) >> 23);  // 9-bit reverse
        int r1 = (int)(__brev((unsigned)i1) >> 23);
        X[PAD(i0)] = make_double2((double)seqf[r0], 0.0);
        X[PAD(i1)] = make_double2((double)seqf[r1], 0.0);
    }
    __builtin_amdgcn_wave_barrier();

    // stages 1..7: butterflies stay inside the wave's 128-pt chunk
    #pragma unroll
    for (int st = 1; st <= 7; ++st) {
        const int half = 1 << (st - 1);
        const int pos  = tid & (half - 1);
        const int i1   = ((tid >> (st - 1)) << st) + pos;
        const int i2   = i1 + half;
        const double2 wv = W[PAD(pos << (9 - st))];
        const double2 a  = X[PAD(i1)];
        const double2 c  = X[PAD(i2)];
        const double tr = wv.x * c.x - wv.y * c.y;
        const double ti = wv.x * c.y + wv.y * c.x;
        X[PAD(i1)] = make_double2(a.x + tr, a.y + ti);
        X[PAD(i2)] = make_double2(a.x - tr, a.y - ti);
        __builtin_amdgcn_wave_barrier();
    }

    // stages 8,9 cross waves
    #pragma unroll
    for (int st = 8; st <= 9; ++st) {
        __syncthreads();             // B2, B3
        const int half = 1 << (st - 1);
        const int pos  = tid & (half - 1);
        const int i1   = ((tid >> (st - 1)) << st) + pos;
        const int i2   = i1 + half;
        const double2 wv = W[PAD(pos << (9 - st))];
        const double2 a  = X[PAD(i1)];
        const double2 c  = X[PAD(i2)];
        const double tr = wv.x * c.x - wv.y * c.y;
        const double ti = wv.x * c.y + wv.y * c.x;
        X[PAD(i1)] = make_double2(a.x + tr, a.y + ti);
        X[PAD(i2)] = make_double2(a.x - tr, a.y - ti);
    }
    __syncthreads();                 // B4

    // ---- squared amplitudes (ordering-equivalent), DC zeroed ----
    {
        double2 v = X[PAD(tid)];
        amp2[PAD(tid)] = (tid == 0) ? 0.0 : (v.x * v.x + v.y * v.y);
        if (tid == 0) {
            double2 vn = X[PAD(TLEN / 2)];
            amp2[PAD(TLEN / 2)] = vn.x * vn.x + vn.y * vn.y;
        }
    }
    __syncthreads();                 // B5

    // ---- top-4 by wave 0 (shfl butterflies; smallest-index tie-break) ----
    if (wave == 0) {
        for (int q = 0; q < KP; ++q) {
            double v  = amp2[PAD(lane)];
            int    vi = lane;
            #pragma unroll
            for (int j = 1; j < 4; ++j) {
                double u = amp2[PAD(lane + 64 * j)];
                if (u > v) { v = u; vi = lane + 64 * j; }
            }
            if (lane == 0) {
                double u = amp2[PAD(256)];
                if (u > v) { v = u; vi = 256; }
            }
            #pragma unroll
            for (int off = 32; off > 0; off >>= 1) {
                double ov = __shfl_xor(v, off, 64);
                int    oi = __shfl_xor(vi, off, 64);
                if (ov > v || (ov == v && oi < vi)) { v = ov; vi = oi; }
            }
            if (lane == 0) {
                bestv[q] = v;
                besti[q] = vi;
                amp2[PAD(vi)] = -1.0;   // exclude (amp2 >= 0)
            }
            __builtin_amdgcn_wave_barrier();
        }
        if (lane < KP) {
            int ki = besti[lane];
            if (ki < 1) ki = 1;
            int P = TLEN / ki;
            P = P < MINP ? MINP : (P > PMAXV ? PMAXV : P);
            int cyc = TLEN / P;      // 8..32
            prm_ws[(size_t)s * KP + lane] = make_int4(P, cyc, TLEN - cyc * P, 0);
            // sqrt only for the 4 winners: identical bits to sqrt-then-select
            out_a[(size_t)s * KP + lane] = (float)sqrt(bestv[lane]);
        }
    }
}

// ============================================================================
// Kernel 2: pure streaming writer. Tiny LDS -> full occupancy, no convoy.
// ============================================================================
__global__ __launch_bounds__(256) void writer_kernel(
    const float* __restrict__ seq_ws,
    const int4*  __restrict__ prm_ws,
    float* __restrict__ out_g,
    float* __restrict__ out_m)
{
    const int s   = blockIdx.x;
    const int tid = threadIdx.x;

    __shared__ float seqf[TLEN];
    __shared__ int   Ps[KP], Cs[KP], Bs[KP];

    if (tid < TLEN / 4)
        ((nfloat4*)seqf)[tid] = ((const nfloat4*)(seq_ws + (size_t)s * TLEN))[tid];
    if (tid < KP) {
        int4 p = prm_ws[(size_t)s * KP + tid];
        Ps[tid] = p.x; Cs[tid] = p.y; Bs[tid] = p.z;
    }
    __syncthreads();

    float* og = out_g + (size_t)s * (KP * CMAXV * PMAXV);
    float* om = out_m + (size_t)s * (KP * CMAXV * PMAXV);
    const int pp = (tid & 15) << 2;      // p offset 0..60 step 4
    #pragma unroll
    for (int r = tid >> 4; r < KP * CMAXV; r += 16) {
        const int k = r >> 5;            // / CMAXV
        const int c = r & (CMAXV - 1);
        const int P = Ps[k], cyc = Cs[k], base = Bs[k];
        nfloat4 g = (nfloat4)(0.f, 0.f, 0.f, 0.f);
        nfloat4 m = (nfloat4)(0.f, 0.f, 0.f, 0.f);
        if (c < cyc) {
            const int idx = base + c * P + pp;   // in-bounds whenever p < P
            if (pp     < P) { g.x = seqf[idx];     m.x = 1.f; }
            if (pp + 1 < P) { g.y = seqf[idx + 1]; m.y = 1.f; }
            if (pp + 2 < P) { g.z = seqf[idx + 2]; m.z = 1.f; }
            if (pp + 3 < P) { g.w = seqf[idx + 3]; m.w = 1.f; }
        }
        __builtin_nontemporal_store(g, (nfloat4*)(og + r * PMAXV + pp));
        __builtin_nontemporal_store(m, (nfloat4*)(om + r * PMAXV + pp));
    }
}

extern "C" void kernel_launch(void* const* d_in, const int* in_sizes, int n_in,
                              void* d_out, int out_size, void* d_ws, size_t ws_size,
                              hipStream_t stream) {
    const float* x = (const float*)d_in[0];
    float* out = (float*)d_out;
    float* og = out;              // gathered: [B,N,K,Cmax,Pmax]
    float* om = out + OUTG;       // mask:     same shape
    float* oa = om + OUTG;        // kamp:     [B,N,K]

    // workspace layout
    char* ws = (char*)d_ws;
    double2* Wg   = (double2*)ws;                       // 4 KB
    float*  seqw  = (float*)(ws + 8192);                // 8 MB
    int4*   prmw  = (int4*)(ws + 8192 + (size_t)NSEQ * TLEN * 4);  // 256 KB

    twiddle_setup<<<dim3(1), dim3(256), 0, stream>>>(Wg);
    param_kernel<<<dim3(NSEQ), dim3(256), 0, stream>>>(x, Wg, seqw, prmw, oa);
    writer_kernel<<<dim3(NSEQ), dim3(256), 0, stream>>>(seqw, prmw, og, om);
}

// Round 7
// 276.861 us; speedup vs baseline: 1.0920x; 1.0920x over previous
//
#include <hip/hip_runtime.h>
#include <math.h>

#define TLEN 512
#define NCH  128
#define KP   4
#define PMAXV 64
#define CMAXV 32
#define MINP 16
#define NSEQ 4096   // B*N = 32*128
#define OUTG ((size_t)NSEQ * KP * CMAXV * PMAXV)   // 33,554,432

// pad-per-8 for 8B (double) LDS elements: breaks power-of-2 bank strides
#define PAD8(i) ((i) + ((i) >> 3))
#define XP   580            // >= PAD8(511)+1 = 575
#define SEQP 520            // padded f32 sequence row

typedef float nfloat4 __attribute__((ext_vector_type(4)));

// ---- tiny setup kernel: twiddle table W[j] = exp(-2*pi*i*j/512) ----
__global__ void twiddle_setup(double2* __restrict__ Wg) {
    const int j = threadIdx.x;    // 256 threads
    double ang = -6.283185307179586476925286766559 * (double)j / (double)TLEN;
    double sv, cv;
    sincos(ang, &sv, &cv);
    Wg[j] = make_double2(cv, sv);
}

// One block = 4 sequences, one WAVE per sequence. Zero block barriers after
// the input stage; waves run independently (FFT latency of some waves hides
// behind store streaming of others).
__global__ __launch_bounds__(256) void periodicity_kernel(
    const float* __restrict__ x,
    const double2* __restrict__ Wg,
    float* __restrict__ out_g,
    float* __restrict__ out_m,
    float* __restrict__ out_a)
{
    const int tid  = threadIdx.x;
    const int lane = tid & 63;
    const int w    = tid >> 6;          // wave id = local sequence id
    const int s0   = blockIdx.x << 2;   // first sequence of this block
    const int b    = s0 >> 7;           // all 4 seqs share b (4 | 128)
    const int n0   = s0 & (NCH - 1);    // multiple of 4

    __shared__ float   seqf[4 * SEQP];
    __shared__ double  re[4 * XP];
    __shared__ double  im[4 * XP];
    __shared__ double2 W[256];

    // ---- cooperative load: thread -> (t = tid>>2, col = tid&3) ----
    {
        const int col = tid & 3;
        const int t0  = tid >> 2;       // 0..63
        const float* base = x + (size_t)b * TLEN * NCH + n0 + col;
        #pragma unroll
        for (int it = 0; it < 8; ++it) {
            const int t = t0 + 64 * it;
            seqf[col * SEQP + t] = base[(size_t)t * NCH];
        }
        W[tid] = Wg[tid];
    }
    __syncthreads();                    // the ONLY block barrier

    float*  sf = seqf + w * SEQP;
    double* RE = re + w * XP;
    double* IM = im + w * XP;

    // ---- bit-reverse scatter (wave-local): 8 fills/lane covers 512 pts ----
    #pragma unroll
    for (int u = 0; u < 8; ++u) {
        const int i = lane + 64 * u;
        const int r = (int)(__brev((unsigned)i) >> 23);   // 9-bit reverse
        RE[PAD8(i)] = (double)sf[r];
        IM[PAD8(i)] = 0.0;
    }
    __builtin_amdgcn_wave_barrier();

    // ---- 9 radix-2 DIT stages, all intra-wave (4 butterflies/lane) ----
    for (int st = 1; st <= 9; ++st) {
        const int half = 1 << (st - 1);
        #pragma unroll
        for (int u = 0; u < 4; ++u) {
            const int j   = lane + 64 * u;
            const int pos = j & (half - 1);
            const int i1  = ((j >> (st - 1)) << st) + pos;
            const int i2  = i1 + half;
            const double2 wv = W[pos << (9 - st)];
            const double ar = RE[PAD8(i1)], ai = IM[PAD8(i1)];
            const double cr = RE[PAD8(i2)], ci = IM[PAD8(i2)];
            const double tr = wv.x * cr - wv.y * ci;
            const double ti = wv.x * ci + wv.y * cr;
            RE[PAD8(i1)] = ar + tr;  IM[PAD8(i1)] = ai + ti;
            RE[PAD8(i2)] = ar - tr;  IM[PAD8(i2)] = ai - ti;
        }
        __builtin_amdgcn_wave_barrier();
    }

    // ---- squared amplitudes in-place into RE (bins 0..256 only) ----
    #pragma unroll
    for (int u = 0; u < 4; ++u) {
        const int k = lane + 64 * u;
        const double xr = RE[PAD8(k)], xi = IM[PAD8(k)];
        RE[PAD8(k)] = (k == 0) ? 0.0 : (xr * xr + xi * xi);
    }
    if (lane == 0) {
        const double xr = RE[PAD8(256)], xi = IM[PAD8(256)];
        RE[PAD8(256)] = xr * xr + xi * xi;
    }
    __builtin_amdgcn_wave_barrier();

    // ---- top-4 (wave-local shfl butterflies; smallest-index tie-break) ----
    double bv0, bv1, bv2, bv3;
    int    bi0, bi1, bi2, bi3;
    #pragma unroll
    for (int q = 0; q < KP; ++q) {
        double v  = RE[PAD8(lane)];
        int    vi = lane;
        #pragma unroll
        for (int u = 1; u < 4; ++u) {          // increasing index, strict >
            const double uu = RE[PAD8(lane + 64 * u)];
            if (uu > v) { v = uu; vi = lane + 64 * u; }
        }
        if (lane == 0) {
            const double uu = RE[PAD8(256)];
            if (uu > v) { v = uu; vi = 256; }
        }
        #pragma unroll
        for (int off = 32; off > 0; off >>= 1) {
            const double ov = __shfl_xor(v, off, 64);
            const int    oi = __shfl_xor(vi, off, 64);
            if (ov > v || (ov == v && oi < vi)) { v = ov; vi = oi; }
        }
        // all lanes now hold the winner
        if (q == 0) { bv0 = v; bi0 = vi; }
        else if (q == 1) { bv1 = v; bi1 = vi; }
        else if (q == 2) { bv2 = v; bi2 = vi; }
        else { bv3 = v; bi3 = vi; }
        if (lane == 0) RE[PAD8(vi)] = -1.0;    // exclude (amp2 >= 0)
        __builtin_amdgcn_wave_barrier();
    }

    // ---- params (in registers, every lane) ----
    int P0, P1, P2, P3, C0, C1, C2, C3, B0, B1, B2, B3;
    {
        int k0 = bi0 < 1 ? 1 : bi0;  P0 = TLEN / k0;
        P0 = P0 < MINP ? MINP : (P0 > PMAXV ? PMAXV : P0);
        C0 = TLEN / P0;  B0 = TLEN - C0 * P0;
        int k1 = bi1 < 1 ? 1 : bi1;  P1 = TLEN / k1;
        P1 = P1 < MINP ? MINP : (P1 > PMAXV ? PMAXV : P1);
        C1 = TLEN / P1;  B1 = TLEN - C1 * P1;
        int k2 = bi2 < 1 ? 1 : bi2;  P2 = TLEN / k2;
        P2 = P2 < MINP ? MINP : (P2 > PMAXV ? PMAXV : P2);
        C2 = TLEN / P2;  B2 = TLEN - C2 * P2;
        int k3 = bi3 < 1 ? 1 : bi3;  P3 = TLEN / k3;
        P3 = P3 < MINP ? MINP : (P3 > PMAXV ? PMAXV : P3);
        C3 = TLEN / P3;  B3 = TLEN - C3 * P3;
    }
    const int s = s0 + w;
    if (lane == 0) {
        // sqrt only for winners: bit-identical to sqrt-then-select
        out_a[(size_t)s * KP + 0] = (float)sqrt(bv0);
        out_a[(size_t)s * KP + 1] = (float)sqrt(bv1);
        out_a[(size_t)s * KP + 2] = (float)sqrt(bv2);
        out_a[(size_t)s * KP + 3] = (float)sqrt(bv3);
    }

    // ---- gather + mask, plain float4 stores (wave-local sequence) ----
    float* og = out_g + (size_t)s * (KP * CMAXV * PMAXV);
    float* om = out_m + (size_t)s * (KP * CMAXV * PMAXV);
    const int pp = (lane & 15) << 2;       // p offset 0..60 step 4
    for (int r = lane >> 4; r < KP * CMAXV; r += 4) {
        const int k = r >> 5;              // / CMAXV
        const int c = r & (CMAXV - 1);
        const int P    = k == 0 ? P0 : k == 1 ? P1 : k == 2 ? P2 : P3;
        const int cyc  = k == 0 ? C0 : k == 1 ? C1 : k == 2 ? C2 : C3;
        const int base = k == 0 ? B0 : k == 1 ? B1 : k == 2 ? B2 : B3;
        nfloat4 g = (nfloat4)(0.f, 0.f, 0.f, 0.f);
        nfloat4 m = (nfloat4)(0.f, 0.f, 0.f, 0.f);
        if (c < cyc) {
            const int idx = base + c * P + pp;   // in-bounds whenever p < P
            if (pp     < P) { g.x = sf[idx];     m.x = 1.f; }
            if (pp + 1 < P) { g.y = sf[idx + 1]; m.y = 1.f; }
            if (pp + 2 < P) { g.z = sf[idx + 2]; m.z = 1.f; }
            if (pp + 3 < P) { g.w = sf[idx + 3]; m.w = 1.f; }
        }
        *(nfloat4*)(og + r * PMAXV + pp) = g;
        *(nfloat4*)(om + r * PMAXV + pp) = m;
    }
}

extern "C" void kernel_launch(void* const* d_in, const int* in_sizes, int n_in,
                              void* d_out, int out_size, void* d_ws, size_t ws_size,
                              hipStream_t stream) {
    const float* x = (const float*)d_in[0];
    float* out = (float*)d_out;
    float* og = out;              // gathered: [B,N,K,Cmax,Pmax]
    float* om = out + OUTG;       // mask:     same shape
    float* oa = om + OUTG;        // kamp:     [B,N,K]
    double2* Wg = (double2*)d_ws; // 4 KB twiddle table

    twiddle_setup<<<dim3(1), dim3(256), 0, stream>>>(Wg);
    periodicity_kernel<<<dim3(NSEQ / 4), dim3(256), 0, stream>>>(x, Wg, og, om, oa);
}

// Round 8
// 273.213 us; speedup vs baseline: 1.1066x; 1.0134x over previous
//
#include <hip/hip_runtime.h>
#include <math.h>

#define TLEN 512
#define NCH  128
#define KP   4
#define PMAXV 64
#define CMAXV 32
#define MINP 16
#define NSEQ 4096   // B*N = 32*128
#define OUTG ((size_t)NSEQ * KP * CMAXV * PMAXV)   // 33,554,432

// pad-per-8 for 8B (double) LDS elements: breaks power-of-2 bank strides
#define PAD8(i) ((i) + ((i) >> 3))
#define XP   580            // >= PAD8(511)+1 = 575
#define SEQP 520            // padded f32 sequence row

typedef float nfloat4 __attribute__((ext_vector_type(4)));

// One block = 4 sequences, one WAVE per sequence. One block barrier total.
// Twiddles computed in-block (R1 measured this neutral vs a table kernel);
// top-4 fully register-resident (no amp2 LDS round trip, no barriers).
__global__ __launch_bounds__(256) void periodicity_kernel(
    const float* __restrict__ x,
    float* __restrict__ out_g,
    float* __restrict__ out_m,
    float* __restrict__ out_a)
{
    const int tid  = threadIdx.x;
    const int lane = tid & 63;
    const int w    = tid >> 6;          // wave id = local sequence id
    const int s0   = blockIdx.x << 2;   // first sequence of this block
    const int b    = s0 >> 7;           // all 4 seqs share b (4 | 128)
    const int n0   = s0 & (NCH - 1);    // multiple of 4

    __shared__ float   seqf[4 * SEQP];
    __shared__ double  re[4 * XP];
    __shared__ double  im[4 * XP];
    __shared__ double2 W[256];

    // ---- cooperative load + in-block twiddle table ----
    {
        const int col = tid & 3;
        const int t0  = tid >> 2;       // 0..63
        const float* base = x + (size_t)b * TLEN * NCH + n0 + col;
        #pragma unroll
        for (int it = 0; it < 8; ++it) {
            const int t = t0 + 64 * it;
            seqf[col * SEQP + t] = base[(size_t)t * NCH];
        }
        double ang = -6.283185307179586476925286766559 * (double)tid / (double)TLEN;
        double sv, cv;
        sincos(ang, &sv, &cv);
        W[tid] = make_double2(cv, sv);
    }
    __syncthreads();                    // the ONLY block barrier

    float*  sf = seqf + w * SEQP;
    double* RE = re + w * XP;
    double* IM = im + w * XP;

    // ---- bit-reverse scatter (wave-local): 8 fills/lane covers 512 pts ----
    #pragma unroll
    for (int u = 0; u < 8; ++u) {
        const int i = lane + 64 * u;
        const int r = (int)(__brev((unsigned)i) >> 23);   // 9-bit reverse
        RE[PAD8(i)] = (double)sf[r];
        IM[PAD8(i)] = 0.0;
    }
    __builtin_amdgcn_wave_barrier();

    // ---- 9 radix-2 DIT stages, all intra-wave (4 butterflies/lane) ----
    for (int st = 1; st <= 9; ++st) {
        const int half = 1 << (st - 1);
        #pragma unroll
        for (int u = 0; u < 4; ++u) {
            const int j   = lane + 64 * u;
            const int pos = j & (half - 1);
            const int i1  = ((j >> (st - 1)) << st) + pos;
            const int i2  = i1 + half;
            const double2 wv = W[pos << (9 - st)];
            const double ar = RE[PAD8(i1)], ai = IM[PAD8(i1)];
            const double cr = RE[PAD8(i2)], ci = IM[PAD8(i2)];
            const double tr = wv.x * cr - wv.y * ci;
            const double ti = wv.x * ci + wv.y * cr;
            RE[PAD8(i1)] = ar + tr;  IM[PAD8(i1)] = ai + ti;
            RE[PAD8(i2)] = ar - tr;  IM[PAD8(i2)] = ai - ti;
        }
        __builtin_amdgcn_wave_barrier();
    }

    // ---- squared amplitudes straight into registers (bins 0..256) ----
    // lane owns bins {lane, lane+64, lane+128, lane+192}; lane 0 also 256.
    double a[5];
    int    bins[5];
    #pragma unroll
    for (int u = 0; u < 4; ++u) {
        const int k = lane + 64 * u;
        const double xr = RE[PAD8(k)], xi = IM[PAD8(k)];
        a[u]    = (k == 0) ? 0.0 : (xr * xr + xi * xi);
        bins[u] = k;
    }
    a[4]    = -1.0;                    // non-owners: never selected
    bins[4] = 256;
    if (lane == 0) {
        const double xr = RE[PAD8(256)], xi = IM[PAD8(256)];
        a[4] = xr * xr + xi * xi;
    }

    // ---- top-4, fully in registers (smallest-index tie-break) ----
    double bv0, bv1, bv2, bv3;
    int    bi0, bi1, bi2, bi3;
    #pragma unroll
    for (int q = 0; q < KP; ++q) {
        // local scan ascending bins with strict > : smallest index on ties
        double v  = a[0];
        int    vi = bins[0];
        #pragma unroll
        for (int j = 1; j < 5; ++j)
            if (a[j] > v) { v = a[j]; vi = bins[j]; }
        // 64-lane butterfly argmax, smallest-index tie-break
        #pragma unroll
        for (int off = 32; off > 0; off >>= 1) {
            const double ov = __shfl_xor(v, off, 64);
            const int    oi = __shfl_xor(vi, off, 64);
            if (ov > v || (ov == v && oi < vi)) { v = ov; vi = oi; }
        }
        if (q == 0) { bv0 = v; bi0 = vi; }
        else if (q == 1) { bv1 = v; bi1 = vi; }
        else if (q == 2) { bv2 = v; bi2 = vi; }
        else { bv3 = v; bi3 = vi; }
        // mark winner taken (register exclusion, no LDS)
        #pragma unroll
        for (int j = 0; j < 5; ++j)
            if (bins[j] == vi) a[j] = -1.0;
    }

    // ---- params (in registers, every lane) ----
    int P0, P1, P2, P3, C0, C1, C2, C3, B0, B1, B2, B3;
    {
        int k0 = bi0 < 1 ? 1 : bi0;  P0 = TLEN / k0;
        P0 = P0 < MINP ? MINP : (P0 > PMAXV ? PMAXV : P0);
        C0 = TLEN / P0;  B0 = TLEN - C0 * P0;
        int k1 = bi1 < 1 ? 1 : bi1;  P1 = TLEN / k1;
        P1 = P1 < MINP ? MINP : (P1 > PMAXV ? PMAXV : P1);
        C1 = TLEN / P1;  B1 = TLEN - C1 * P1;
        int k2 = bi2 < 1 ? 1 : bi2;  P2 = TLEN / k2;
        P2 = P2 < MINP ? MINP : (P2 > PMAXV ? PMAXV : P2);
        C2 = TLEN / P2;  B2 = TLEN - C2 * P2;
        int k3 = bi3 < 1 ? 1 : bi3;  P3 = TLEN / k3;
        P3 = P3 < MINP ? MINP : (P3 > PMAXV ? PMAXV : P3);
        C3 = TLEN / P3;  B3 = TLEN - C3 * P3;
    }
    const int s = s0 + w;
    if (lane == 0) {
        // sqrt only for winners: bit-identical to sqrt-then-select
        out_a[(size_t)s * KP + 0] = (float)sqrt(bv0);
        out_a[(size_t)s * KP + 1] = (float)sqrt(bv1);
        out_a[(size_t)s * KP + 2] = (float)sqrt(bv2);
        out_a[(size_t)s * KP + 3] = (float)sqrt(bv3);
    }

    float* og = out_g + (size_t)s * (KP * CMAXV * PMAXV);
    float* om = out_m + (size_t)s * (KP * CMAXV * PMAXV);
    const int pp = (lane & 15) << 2;       // p offset 0..60 step 4

    // ---- mask stores first: zero LDS dependency, fills the store pipe ----
    for (int r = lane >> 4; r < KP * CMAXV; r += 4) {
        const int k = r >> 5;              // / CMAXV
        const int c = r & (CMAXV - 1);
        const int P    = k == 0 ? P0 : k == 1 ? P1 : k == 2 ? P2 : P3;
        const int cyc  = k == 0 ? C0 : k == 1 ? C1 : k == 2 ? C2 : C3;
        nfloat4 m = (nfloat4)(0.f, 0.f, 0.f, 0.f);
        if (c < cyc) {
            m.x = (pp     < P) ? 1.f : 0.f;
            m.y = (pp + 1 < P) ? 1.f : 0.f;
            m.z = (pp + 2 < P) ? 1.f : 0.f;
            m.w = (pp + 3 < P) ? 1.f : 0.f;
        }
        *(nfloat4*)(om + r * PMAXV + pp) = m;
    }

    // ---- gathered stores (LDS reads of wave-local sequence) ----
    for (int r = lane >> 4; r < KP * CMAXV; r += 4) {
        const int k = r >> 5;
        const int c = r & (CMAXV - 1);
        const int P    = k == 0 ? P0 : k == 1 ? P1 : k == 2 ? P2 : P3;
        const int cyc  = k == 0 ? C0 : k == 1 ? C1 : k == 2 ? C2 : C3;
        const int base = k == 0 ? B0 : k == 1 ? B1 : k == 2 ? B2 : B3;
        nfloat4 g = (nfloat4)(0.f, 0.f, 0.f, 0.f);
        if (c < cyc) {
            const int idx = base + c * P + pp;   // in-bounds whenever p < P
            if (pp     < P) g.x = sf[idx];
            if (pp + 1 < P) g.y = sf[idx + 1];
            if (pp + 2 < P) g.z = sf[idx + 2];
            if (pp + 3 < P) g.w = sf[idx + 3];
        }
        *(nfloat4*)(og + r * PMAXV + pp) = g;
    }
}

extern "C" void kernel_launch(void* const* d_in, const int* in_sizes, int n_in,
                              void* d_out, int out_size, void* d_ws, size_t ws_size,
                              hipStream_t stream) {
    const float* x = (const float*)d_in[0];
    float* out = (float*)d_out;
    float* og = out;              // gathered: [B,N,K,Cmax,Pmax]
    float* om = out + OUTG;       // mask:     same shape
    float* oa = om + OUTG;        // kamp:     [B,N,K]

    periodicity_kernel<<<dim3(NSEQ / 4), dim3(256), 0, stream>>>(x, og, om, oa);
}

// Round 9
// 269.528 us; speedup vs baseline: 1.1217x; 1.0137x over previous
//
#include <hip/hip_runtime.h>
#include <math.h>

#define TLEN 512
#define NCH  128
#define KP   4
#define PMAXV 64
#define CMAXV 32
#define MINP 16
#define NSEQ 4096   // B*N = 32*128
#define OUTG ((size_t)NSEQ * KP * CMAXV * PMAXV)   // 33,554,432

// pad-per-8 for 16B (double2) LDS elements: breaks power-of-2 bank strides
#define PAD8(i) ((i) + ((i) >> 3))
#define ZP   290            // >= PAD8(255)+1 = 287
#define SEQP 520            // padded f32 sequence row

typedef float nfloat4 __attribute__((ext_vector_type(4)));

// One block = 4 sequences, one WAVE per sequence; one block barrier total.
// Real-input 512-pt FFT via 256-pt complex FFT (z[t]=x[2t]+i*x[2t+1]) +
// register-only untangle to amp^2. 64 LDS ops/lane vs 288 in the radix-2-512
// version; LDS 30.8 KB -> 5 blocks/CU.
__global__ __launch_bounds__(256) void periodicity_kernel(
    const float* __restrict__ x,
    float* __restrict__ out_g,
    float* __restrict__ out_m,
    float* __restrict__ out_a)
{
    const int tid  = threadIdx.x;
    const int lane = tid & 63;
    const int w    = tid >> 6;          // wave id = local sequence id
    const int s0   = blockIdx.x << 2;   // first sequence of this block
    const int b    = s0 >> 7;           // all 4 seqs share b (4 | 128)
    const int n0   = s0 & (NCH - 1);    // multiple of 4

    __shared__ float   seqf[4 * SEQP];
    __shared__ double2 Z[4 * ZP];
    __shared__ double2 W[256];          // W_512^j, j=0..255

    // ---- cooperative load + in-block twiddle table ----
    {
        const int col = tid & 3;
        const int t0  = tid >> 2;       // 0..63
        const float* base = x + (size_t)b * TLEN * NCH + n0 + col;
        #pragma unroll
        for (int it = 0; it < 8; ++it) {
            const int t = t0 + 64 * it;
            seqf[col * SEQP + t] = base[(size_t)t * NCH];
        }
        double ang = -6.283185307179586476925286766559 * (double)tid / (double)TLEN;
        double sv, cv;
        sincos(ang, &sv, &cv);
        W[tid] = make_double2(cv, sv);
    }
    __syncthreads();                    // the ONLY block barrier

    float*   sf = seqf + w * SEQP;
    double2* Zw = Z + w * ZP;

    // ---- pack z[t]=x[2t]+i*x[2t+1], bit-reverse (8-bit), 4 pts/lane ----
    #pragma unroll
    for (int u = 0; u < 4; ++u) {
        const int i = lane + 64 * u;
        const int r = (int)(__brev((unsigned)i) >> 24);   // 8-bit reverse
        const float2 p = ((const float2*)sf)[r];          // x[2r], x[2r+1]
        Zw[PAD8(i)] = make_double2((double)p.x, (double)p.y);
    }
    __builtin_amdgcn_wave_barrier();

    // ---- 8 radix-2 DIT stages over 256 complex pts (2 butterflies/lane) ----
    for (int st = 1; st <= 8; ++st) {
        const int half = 1 << (st - 1);
        #pragma unroll
        for (int u = 0; u < 2; ++u) {
            const int j   = lane + 64 * u;                // butterfly id 0..127
            const int pos = j & (half - 1);
            const int i1  = ((j >> (st - 1)) << st) + pos;
            const int i2  = i1 + half;
            // W_256^(pos<<(8-st)) == W_512^(pos<<(9-st))
            const double2 wv = W[pos << (9 - st)];
            const double2 a  = Zw[PAD8(i1)];
            const double2 c  = Zw[PAD8(i2)];
            const double tr = wv.x * c.x - wv.y * c.y;
            const double ti = wv.x * c.y + wv.y * c.x;
            Zw[PAD8(i1)] = make_double2(a.x + tr, a.y + ti);
            Zw[PAD8(i2)] = make_double2(a.x - tr, a.y - ti);
        }
        __builtin_amdgcn_wave_barrier();
    }

    // ---- untangle to amp^2 straight into registers (bins 0..256) ----
    // E[k]=(Z[k]+conj(Z[256-k]))/2, O[k]=-i(Z[k]-conj(Z[256-k]))/2,
    // X[k]=E[k]+W_512^k*O[k];  X[256]=Re(Z0)-Im(Z0).
    double av[5];
    int    bins[5];
    #pragma unroll
    for (int u = 0; u < 4; ++u) {
        const int k = lane + 64 * u;
        const double2 zk = Zw[PAD8(k)];
        const double2 zm = Zw[PAD8((256 - k) & 255)];
        const double gr = 0.5 * (zk.x + zm.x);
        const double gi = 0.5 * (zk.y - zm.y);
        const double hr = 0.5 * (zk.y + zm.y);
        const double hi = 0.5 * (zm.x - zk.x);
        const double2 wv = W[k];
        const double xr = gr + wv.x * hr - wv.y * hi;
        const double xi = gi + wv.x * hi + wv.y * hr;
        av[u]   = (k == 0) ? 0.0 : (xr * xr + xi * xi);
        bins[u] = k;
    }
    av[4]   = -1.0;                    // non-owners: never selected
    bins[4] = 256;
    if (lane == 0) {
        const double2 z0 = Zw[PAD8(0)];
        const double nyq = z0.x - z0.y;
        av[4] = nyq * nyq;
    }

    // ---- top-4, fully in registers (smallest-index tie-break) ----
    double bv0, bv1, bv2, bv3;
    int    bi0, bi1, bi2, bi3;
    #pragma unroll
    for (int q = 0; q < KP; ++q) {
        double v  = av[0];
        int    vi = bins[0];
        #pragma unroll
        for (int j = 1; j < 5; ++j)
            if (av[j] > v) { v = av[j]; vi = bins[j]; }
        #pragma unroll
        for (int off = 32; off > 0; off >>= 1) {
            const double ov = __shfl_xor(v, off, 64);
            const int    oi = __shfl_xor(vi, off, 64);
            if (ov > v || (ov == v && oi < vi)) { v = ov; vi = oi; }
        }
        if (q == 0) { bv0 = v; bi0 = vi; }
        else if (q == 1) { bv1 = v; bi1 = vi; }
        else if (q == 2) { bv2 = v; bi2 = vi; }
        else { bv3 = v; bi3 = vi; }
        #pragma unroll
        for (int j = 0; j < 5; ++j)
            if (bins[j] == vi) av[j] = -1.0;
    }

    // ---- params (in registers, every lane) ----
    int P0, P1, P2, P3, C0, C1, C2, C3, B0, B1, B2, B3;
    {
        int k0 = bi0 < 1 ? 1 : bi0;  P0 = TLEN / k0;
        P0 = P0 < MINP ? MINP : (P0 > PMAXV ? PMAXV : P0);
        C0 = TLEN / P0;  B0 = TLEN - C0 * P0;
        int k1 = bi1 < 1 ? 1 : bi1;  P1 = TLEN / k1;
        P1 = P1 < MINP ? MINP : (P1 > PMAXV ? PMAXV : P1);
        C1 = TLEN / P1;  B1 = TLEN - C1 * P1;
        int k2 = bi2 < 1 ? 1 : bi2;  P2 = TLEN / k2;
        P2 = P2 < MINP ? MINP : (P2 > PMAXV ? PMAXV : P2);
        C2 = TLEN / P2;  B2 = TLEN - C2 * P2;
        int k3 = bi3 < 1 ? 1 : bi3;  P3 = TLEN / k3;
        P3 = P3 < MINP ? MINP : (P3 > PMAXV ? PMAXV : P3);
        C3 = TLEN / P3;  B3 = TLEN - C3 * P3;
    }
    const int s = s0 + w;
    if (lane == 0) {
        // sqrt only for winners: identical bits to sqrt-then-select
        out_a[(size_t)s * KP + 0] = (float)sqrt(bv0);
        out_a[(size_t)s * KP + 1] = (float)sqrt(bv1);
        out_a[(size_t)s * KP + 2] = (float)sqrt(bv2);
        out_a[(size_t)s * KP + 3] = (float)sqrt(bv3);
    }

    float* og = out_g + (size_t)s * (KP * CMAXV * PMAXV);
    float* om = out_m + (size_t)s * (KP * CMAXV * PMAXV);
    const int pp = (lane & 15) << 2;       // p offset 0..60 step 4

    // ---- mask stores first: zero LDS dependency, fills the store pipe ----
    for (int r = lane >> 4; r < KP * CMAXV; r += 4) {
        const int k = r >> 5;              // / CMAXV
        const int c = r & (CMAXV - 1);
        const int P   = k == 0 ? P0 : k == 1 ? P1 : k == 2 ? P2 : P3;
        const int cyc = k == 0 ? C0 : k == 1 ? C1 : k == 2 ? C2 : C3;
        nfloat4 m = (nfloat4)(0.f, 0.f, 0.f, 0.f);
        if (c < cyc) {
            m.x = (pp     < P) ? 1.f : 0.f;
            m.y = (pp + 1 < P) ? 1.f : 0.f;
            m.z = (pp + 2 < P) ? 1.f : 0.f;
            m.w = (pp + 3 < P) ? 1.f : 0.f;
        }
        *(nfloat4*)(om + r * PMAXV + pp) = m;
    }

    // ---- gathered stores (LDS reads of wave-local sequence) ----
    for (int r = lane >> 4; r < KP * CMAXV; r += 4) {
        const int k = r >> 5;
        const int c = r & (CMAXV - 1);
        const int P    = k == 0 ? P0 : k == 1 ? P1 : k == 2 ? P2 : P3;
        const int cyc  = k == 0 ? C0 : k == 1 ? C1 : k == 2 ? C2 : C3;
        const int base = k == 0 ? B0 : k == 1 ? B1 : k == 2 ? B2 : B3;
        nfloat4 g = (nfloat4)(0.f, 0.f, 0.f, 0.f);
        if (c < cyc) {
            const int idx = base + c * P + pp;   // in-bounds whenever p < P
            if (pp     < P) g.x = sf[idx];
            if (pp + 1 < P) g.y = sf[idx + 1];
            if (pp + 2 < P) g.z = sf[idx + 2];
            if (pp + 3 < P) g.w = sf[idx + 3];
        }
        *(nfloat4*)(og + r * PMAXV + pp) = g;
    }
}

extern "C" void kernel_launch(void* const* d_in, const int* in_sizes, int n_in,
                              void* d_out, int out_size, void* d_ws, size_t ws_size,
                              hipStream_t stream) {
    const float* x = (const float*)d_in[0];
    float* out = (float*)d_out;
    float* og = out;              // gathered: [B,N,K,Cmax,Pmax]
    float* om = out + OUTG;       // mask:     same shape
    float* oa = om + OUTG;        // kamp:     [B,N,K]

    periodicity_kernel<<<dim3(NSEQ / 4), dim3(256), 0, stream>>>(x, og, om, oa);
}

// Round 10
// 269.062 us; speedup vs baseline: 1.1236x; 1.0017x over previous
//
#include <hip/hip_runtime.h>
#include <math.h>

#define TLEN 512
#define NCH  128
#define KP   4
#define PMAXV 64
#define CMAXV 32
#define MINP 16
#define NSEQ 4096   // B*N = 32*128
#define OUTG ((size_t)NSEQ * KP * CMAXV * PMAXV)   // 33,554,432

// pad-per-8 for 16B (double2) LDS elements: breaks power-of-2 bank strides
#define PAD8(i) ((i) + ((i) >> 3))
#define ZP   290            // >= PAD8(255)+1 = 287
#define SEQP 520            // padded f32 sequence row

typedef float nfloat4 __attribute__((ext_vector_type(4)));

// One block = 4 sequences, one WAVE per sequence; one block barrier total.
// Real-input 512-pt FFT via 256-pt complex FFT + register untangle.
// Store phase: k-hoisted merged loop (params + mask row computed once per k).
__global__ __launch_bounds__(256) void periodicity_kernel(
    const float* __restrict__ x,
    float* __restrict__ out_g,
    float* __restrict__ out_m,
    float* __restrict__ out_a)
{
    const int tid  = threadIdx.x;
    const int lane = tid & 63;
    const int w    = tid >> 6;          // wave id = local sequence id
    const int s0   = blockIdx.x << 2;   // first sequence of this block
    const int b    = s0 >> 7;           // all 4 seqs share b (4 | 128)
    const int n0   = s0 & (NCH - 1);    // multiple of 4

    __shared__ float   seqf[4 * SEQP];
    __shared__ double2 Z[4 * ZP];
    __shared__ double2 W[256];          // W_512^j, j=0..255

    // ---- cooperative load + in-block twiddle table ----
    {
        const int col = tid & 3;
        const int t0  = tid >> 2;       // 0..63
        const float* base = x + (size_t)b * TLEN * NCH + n0 + col;
        #pragma unroll
        for (int it = 0; it < 8; ++it) {
            const int t = t0 + 64 * it;
            seqf[col * SEQP + t] = base[(size_t)t * NCH];
        }
        double ang = -6.283185307179586476925286766559 * (double)tid / (double)TLEN;
        double sv, cv;
        sincos(ang, &sv, &cv);
        W[tid] = make_double2(cv, sv);
    }
    __syncthreads();                    // the ONLY block barrier

    float*   sf = seqf + w * SEQP;
    double2* Zw = Z + w * ZP;

    // ---- pack z[t]=x[2t]+i*x[2t+1], bit-reverse (8-bit), 4 pts/lane ----
    #pragma unroll
    for (int u = 0; u < 4; ++u) {
        const int i = lane + 64 * u;
        const int r = (int)(__brev((unsigned)i) >> 24);   // 8-bit reverse
        const float2 p = ((const float2*)sf)[r];          // x[2r], x[2r+1]
        Zw[PAD8(i)] = make_double2((double)p.x, (double)p.y);
    }
    __builtin_amdgcn_wave_barrier();

    // ---- 8 radix-2 DIT stages over 256 complex pts (2 butterflies/lane) ----
    for (int st = 1; st <= 8; ++st) {
        const int half = 1 << (st - 1);
        #pragma unroll
        for (int u = 0; u < 2; ++u) {
            const int j   = lane + 64 * u;                // butterfly id 0..127
            const int pos = j & (half - 1);
            const int i1  = ((j >> (st - 1)) << st) + pos;
            const int i2  = i1 + half;
            // W_256^(pos<<(8-st)) == W_512^(pos<<(9-st))
            const double2 wv = W[pos << (9 - st)];
            const double2 a  = Zw[PAD8(i1)];
            const double2 c  = Zw[PAD8(i2)];
            const double tr = wv.x * c.x - wv.y * c.y;
            const double ti = wv.x * c.y + wv.y * c.x;
            Zw[PAD8(i1)] = make_double2(a.x + tr, a.y + ti);
            Zw[PAD8(i2)] = make_double2(a.x - tr, a.y - ti);
        }
        __builtin_amdgcn_wave_barrier();
    }

    // ---- untangle to amp^2 straight into registers (bins 0..256) ----
    double av[5];
    int    bins[5];
    #pragma unroll
    for (int u = 0; u < 4; ++u) {
        const int k = lane + 64 * u;
        const double2 zk = Zw[PAD8(k)];
        const double2 zm = Zw[PAD8((256 - k) & 255)];
        const double gr = 0.5 * (zk.x + zm.x);
        const double gi = 0.5 * (zk.y - zm.y);
        const double hr = 0.5 * (zk.y + zm.y);
        const double hi = 0.5 * (zm.x - zk.x);
        const double2 wv = W[k];
        const double xr = gr + wv.x * hr - wv.y * hi;
        const double xi = gi + wv.x * hi + wv.y * hr;
        av[u]   = (k == 0) ? 0.0 : (xr * xr + xi * xi);
        bins[u] = k;
    }
    av[4]   = -1.0;
    bins[4] = 256;
    if (lane == 0) {
        const double2 z0 = Zw[PAD8(0)];
        const double nyq = z0.x - z0.y;
        av[4] = nyq * nyq;
    }

    // ---- top-4, fully in registers (smallest-index tie-break) ----
    double bv[KP];
    int    bi[KP];
    #pragma unroll
    for (int q = 0; q < KP; ++q) {
        double v  = av[0];
        int    vi = bins[0];
        #pragma unroll
        for (int j = 1; j < 5; ++j)
            if (av[j] > v) { v = av[j]; vi = bins[j]; }
        #pragma unroll
        for (int off = 32; off > 0; off >>= 1) {
            const double ov = __shfl_xor(v, off, 64);
            const int    oi = __shfl_xor(vi, off, 64);
            if (ov > v || (ov == v && oi < vi)) { v = ov; vi = oi; }
        }
        bv[q] = v; bi[q] = vi;
        #pragma unroll
        for (int j = 0; j < 5; ++j)
            if (bins[j] == vi) av[j] = -1.0;
    }

    const int s = s0 + w;
    if (lane < KP) {
        // sqrt only for winners: identical bits to sqrt-then-select
        double v = lane == 0 ? bv[0] : lane == 1 ? bv[1] : lane == 2 ? bv[2] : bv[3];
        out_a[(size_t)s * KP + lane] = (float)sqrt(v);
    }

    float* og = out_g + (size_t)s * (KP * CMAXV * PMAXV);
    float* om = out_m + (size_t)s * (KP * CMAXV * PMAXV);
    const int pp   = (lane & 15) << 2;     // p offset 0..60 step 4
    const int crow = lane >> 4;            // 0..3

    // ---- merged store loop, k hoisted (params + mask row once per k) ----
    #pragma unroll
    for (int k = 0; k < KP; ++k) {
        int ki = bi[k] < 1 ? 1 : bi[k];
        int P  = TLEN / ki;
        P = P < MINP ? MINP : (P > PMAXV ? PMAXV : P);
        const int cyc  = TLEN / P;         // 8..32
        const int base = TLEN - cyc * P;

        // mask row pattern — identical for every live row of this k
        nfloat4 mrow;
        mrow.x = (pp     < P) ? 1.f : 0.f;
        mrow.y = (pp + 1 < P) ? 1.f : 0.f;
        mrow.z = (pp + 2 < P) ? 1.f : 0.f;
        mrow.w = (pp + 3 < P) ? 1.f : 0.f;

        float* ogk = og + k * (CMAXV * PMAXV) + pp;
        float* omk = om + k * (CMAXV * PMAXV) + pp;

        #pragma unroll
        for (int c8 = 0; c8 < 8; ++c8) {
            const int c = crow + 4 * c8;   // 0..31
            const bool live = c < cyc;
            nfloat4 m = (nfloat4)(0.f, 0.f, 0.f, 0.f);
            nfloat4 g = (nfloat4)(0.f, 0.f, 0.f, 0.f);
            if (live) {
                m = mrow;
                const int idx = base + c * P + pp;   // in-bounds whenever p < P
                if (pp     < P) g.x = sf[idx];
                if (pp + 1 < P) g.y = sf[idx + 1];
                if (pp + 2 < P) g.z = sf[idx + 2];
                if (pp + 3 < P) g.w = sf[idx + 3];
            }
            *(nfloat4*)(omk + c * PMAXV) = m;
            *(nfloat4*)(ogk + c * PMAXV) = g;
        }
    }
}

extern "C" void kernel_launch(void* const* d_in, const int* in_sizes, int n_in,
                              void* d_out, int out_size, void* d_ws, size_t ws_size,
                              hipStream_t stream) {
    const float* x = (const float*)d_in[0];
    float* out = (float*)d_out;
    float* og = out;              // gathered: [B,N,K,Cmax,Pmax]
    float* om = out + OUTG;       // mask:     same shape
    float* oa = om + OUTG;        // kamp:     [B,N,K]

    periodicity_kernel<<<dim3(NSEQ / 4), dim3(256), 0, stream>>>(x, og, om, oa);
}